// Round 12
// baseline (107.423 us; speedup 1.0000x reference)
//
#include <hip/hip_runtime.h>
#include <hip/hip_bf16.h>
#include <stdint.h>

#define D_MODEL 1024
#define T_SEQ   2048
#define NB      2
#define NH      16
#define HD      64
#define MTOK    4096   // NB*T_SEQ

typedef __bf16  bf16x8 __attribute__((ext_vector_type(8)));
typedef float   f32x4  __attribute__((ext_vector_type(4)));
typedef float   f32x16 __attribute__((ext_vector_type(16)));

#define GPTR(p) ((const __attribute__((address_space(1))) void*)(p))
#define LPTR(p) ((__attribute__((address_space(3))) void*)(p))

static __device__ __forceinline__ ushort f2bf(float f) {
    union { float f; uint32_t u; } c{f};
    uint32_t u = c.u;
    return (ushort)((u + 0x7fff + ((u >> 16) & 1)) >> 16);
}

static __device__ __forceinline__ float bf2f(ushort u) {
    union { uint32_t u; float f; } c{(uint32_t)u << 16};
    return c.f;
}

static __device__ __forceinline__ unsigned cvt_pk_bf16(float lo, float hi) {
    unsigned r;
    asm("v_cvt_pk_bf16_f32 %0, %1, %2" : "=v"(r) : "v"(lo), "v"(hi));
    return r;
}

#if defined(__has_builtin)
#if __has_builtin(__builtin_amdgcn_exp2f)
#define FEXP2(x) __builtin_amdgcn_exp2f(x)
#endif
#endif
#ifndef FEXP2
static __device__ __forceinline__ float fexp2_asm(float x) {
    float r;
    asm("v_exp_f32 %0, %1" : "=v"(r) : "v"(x));
    return r;
}
#define FEXP2(x) fexp2_asm(x)
#endif

// ---------------- Fused prep: LN rows + weight bf16 conversion ----------------
__global__ __launch_bounds__(256) void prep_kernel(const float* __restrict__ x,
                                                   const float* __restrict__ gamma,
                                                   const float* __restrict__ beta,
                                                   ushort* __restrict__ xn,
                                                   const float* __restrict__ a0,
                                                   const float* __restrict__ a1,
                                                   const float* __restrict__ a2,
                                                   ushort* __restrict__ o0,
                                                   ushort* __restrict__ o1,
                                                   ushort* __restrict__ o2) {
    int blk = blockIdx.x;
    int tid = threadIdx.x;
    if (blk >= MTOK) {
        int z = (blk - MTOK) >> 10;
        int cb = (blk - MTOK) & 1023;
        const float* a = (z == 0) ? a0 : (z == 1) ? a1 : a2;
        ushort* o = (z == 0) ? o0 : (z == 1) ? o1 : o2;
        int i = cb * 256 + tid;
        float4 v = ((const float4*)a)[i];
        ushort4 r;
        r.x = f2bf(v.x); r.y = f2bf(v.y); r.z = f2bf(v.z); r.w = f2bf(v.w);
        ((ushort4*)o)[i] = r;
        return;
    }
    int row = blk;
    const float4* xr = (const float4*)(x + (size_t)row * D_MODEL);
    float4 v = xr[tid];
    float s  = v.x + v.y + v.z + v.w;
    float ss = v.x * v.x + v.y * v.y + v.z * v.z + v.w * v.w;
    #pragma unroll
    for (int m = 1; m < 64; m <<= 1) {
        s  += __shfl_xor(s, m);
        ss += __shfl_xor(ss, m);
    }
    __shared__ float red[8];
    int w = tid >> 6, lane = tid & 63;
    if (lane == 0) { red[w] = s; red[4 + w] = ss; }
    __syncthreads();
    s  = red[0] + red[1] + red[2] + red[3];
    ss = red[4] + red[5] + red[6] + red[7];
    float mu   = s * (1.0f / D_MODEL);
    float var  = ss * (1.0f / D_MODEL) - mu * mu;
    float rstd = rsqrtf(var + 1e-5f);
    float4 g = ((const float4*)gamma)[tid];
    float4 b = ((const float4*)beta)[tid];
    ushort4 o;
    o.x = f2bf((v.x - mu) * rstd * g.x + b.x);
    o.y = f2bf((v.y - mu) * rstd * g.y + b.y);
    o.z = f2bf((v.z - mu) * rstd * g.z + b.z);
    o.w = f2bf((v.w - mu) * rstd * g.w + b.w);
    ((ushort4*)(xn + (size_t)row * D_MODEL))[tid] = o;
}

// ---------------- QKV GEMM (unchanged round-9 structure) ----------------
__global__ __launch_bounds__(256) void gemm_qkv(const ushort* __restrict__ A,
                                                const ushort* __restrict__ w0,
                                                const ushort* __restrict__ w1,
                                                const ushort* __restrict__ w2,
                                                ushort* __restrict__ c0,
                                                ushort* __restrict__ c1,
                                                ushort* __restrict__ c2,
                                                int M, int N, int K) {
    const ushort* Bw = (blockIdx.z == 0) ? w0 : (blockIdx.z == 1) ? w1 : w2;
    ushort* C = (blockIdx.z == 0) ? c0 : (blockIdx.z == 1) ? c1 : c2;

    __shared__ __align__(16) ushort lA[2][128 * 64];
    __shared__ __align__(16) ushort lB[2][128 * 64];
    int tid = threadIdx.x;
    int w = tid >> 6, lane = tid & 63;
    int wr = w >> 1, wc = w & 1;
    int l15 = lane & 15, l4 = lane >> 4;
    int row0 = blockIdx.x * 128, col0 = blockIdx.y * 128;

    f32x4 zero = {0.f, 0.f, 0.f, 0.f};
    f32x4 acc[4][4];
    #pragma unroll
    for (int i = 0; i < 4; ++i)
        #pragma unroll
        for (int j = 0; j < 4; ++j) acc[i][j] = zero;

    int sr  = tid >> 3;
    int scc = (((tid & 7) ^ (sr & 7)) << 3);
    int rch[2];
    rch[0] = ((l4)     ^ (l15 & 7)) << 4;
    rch[1] = ((4 + l4) ^ (l15 & 7)) << 4;

    auto STAGE = [&](int buf, int kt) {
        int k0 = kt * 64;
        #pragma unroll
        for (int i = 0; i < 4; ++i) {
            int r = i * 32 + sr;
            const ushort* ga = A + (size_t)(row0 + r) * K + k0 + scc;
            __builtin_amdgcn_global_load_lds(GPTR(ga), LPTR((char*)lA[buf] + i * 4096 + tid * 16), 16, 0, 0);
            const ushort* gb = Bw + (size_t)(col0 + r) * K + k0 + scc;
            __builtin_amdgcn_global_load_lds(GPTR(gb), LPTR((char*)lB[buf] + i * 4096 + tid * 16), 16, 0, 0);
        }
    };

    STAGE(0, 0);
    __syncthreads();

    int buf = 0;
    const int NK = K / 64;
    for (int kt = 0; kt < NK; ++kt) {
        if (kt + 1 < NK) STAGE(buf ^ 1, kt + 1);
        const char* la  = (const char*)lA[buf];
        const char* lb_ = (const char*)lB[buf];
        __builtin_amdgcn_s_setprio(1);
        #pragma unroll
        for (int ks = 0; ks < 2; ++ks) {
            bf16x8 af[4], bfr[4];
            #pragma unroll
            for (int i = 0; i < 4; ++i) {
                int ra = wr * 64 + i * 16 + l15;
                int rb = wc * 64 + i * 16 + l15;
                af[i]  = *(const bf16x8*)(la  + ra * 128 + rch[ks]);
                bfr[i] = *(const bf16x8*)(lb_ + rb * 128 + rch[ks]);
            }
            #pragma unroll
            for (int i = 0; i < 4; ++i)
                #pragma unroll
                for (int j = 0; j < 4; ++j)
                    acc[i][j] = __builtin_amdgcn_mfma_f32_16x16x32_bf16(af[i], bfr[j], acc[i][j], 0, 0, 0);
        }
        __builtin_amdgcn_s_setprio(0);
        __syncthreads();
        buf ^= 1;
    }

    if (blockIdx.z == 2) {
        #pragma unroll
        for (int i = 0; i < 4; ++i) {
            int rbase = row0 + wr * 64 + i * 16 + l4 * 4;
            #pragma unroll
            for (int j = 0; j < 4; ++j) {
                int col = col0 + wc * 64 + j * 16 + l15;
                ushort4 o4;
                o4.x = f2bf(acc[i][j][0]);
                o4.y = f2bf(acc[i][j][1]);
                o4.z = f2bf(acc[i][j][2]);
                o4.w = f2bf(acc[i][j][3]);
                *(ushort4*)&C[(size_t)col * M + rbase] = o4;
            }
        }
    } else {
        float sc = (blockIdx.z == 0) ? 0.18033688011112042f : 1.0f;
        #pragma unroll
        for (int i = 0; i < 4; ++i) {
            int rbase = row0 + wr * 64 + i * 16 + l4 * 4;
            #pragma unroll
            for (int j = 0; j < 4; ++j) {
                int col = col0 + wc * 64 + j * 16 + l15;
                #pragma unroll
                for (int r = 0; r < 4; ++r)
                    C[(size_t)(rbase + r) * N + col] = f2bf(acc[i][j][r] * sc);
            }
        }
    }
}

// ---------------- Flash attention, split-KV x2 (decoupled blocks) ----------
// Grid 1024 blocks (XCD-chunk swizzled): (qt, kv-half p, h, b). 256 threads =
// 4 waves x 32 q-rows; each block does 16 KV tiles. Ring-2 LDS (32 KB),
// single-tile supersteps; 4 blocks/CU -> 4 waves/SIMD (TLP replaces ILP).
// No-max softmax => partials are exact sums: p==0 writes O fp32 to d_out,
// p==1 writes O bf16 to ws; L per half to ws. Combine kernel finishes.
__global__ __launch_bounds__(256, 4) void attn_kernel(const ushort* __restrict__ Q,
                                                      const ushort* __restrict__ Km,
                                                      const ushort* __restrict__ Vt,
                                                      float* __restrict__ o32,
                                                      ushort* __restrict__ o16,
                                                      float* __restrict__ Lp) {
    int bid = blockIdx.x;
    int sw  = (bid & 7) * 128 + (bid >> 3);   // 8 XCD chunks of 128
    int qt = sw & 15, p = (sw >> 4) & 1, h = (sw >> 5) & 15, b = sw >> 9;

    int tid = threadIdx.x, w = tid >> 6, lane = tid & 63;
    int l31 = lane & 31, hh = lane >> 5, x7 = lane & 7;
    size_t head_off = (size_t)b * T_SEQ * D_MODEL + (size_t)h * HD;
    const ushort* Qh  = Q  + head_off;
    const ushort* Kh  = Km + head_off + (size_t)(p * 1024) * D_MODEL;          // half's K rows
    const ushort* Vth = Vt + (size_t)h * HD * MTOK + (size_t)b * T_SEQ + p * 1024;  // [d][tok]

    __shared__ __align__(16) ushort lK[2][64 * 64];   // ring-2, 16 KB
    __shared__ __align__(16) ushort lV[2][64 * 64];   // ring-2, 16 KB

    int qrow = qt * 128 + w * 32 + l31;
    bf16x8 qf[4];
    #pragma unroll
    for (int c = 0; c < 4; ++c)
        qf[c] = *(const bf16x8*)&Qh[(size_t)qrow * D_MODEL + hh * 8 + c * 16];

    // staging (validated XOR-involution): lane stages chunk i=w*128+lane (+64)
    int i0  = w * 128 + lane;
    int r0  = i0 >> 3;
    int cg0 = (i0 & 7) ^ (r0 & 7);
    const ushort* ksrc0 = Kh  + (size_t)r0 * D_MODEL + cg0 * 8;
    const ushort* ksrc1 = ksrc0 + (size_t)8 * D_MODEL;
    const ushort* vsrc0 = Vth + (size_t)r0 * MTOK + cg0 * 8;
    const ushort* vsrc1 = vsrc0 + (size_t)8 * MTOK;

    int chv[4];
    #pragma unroll
    for (int c = 0; c < 4; ++c) chv[c] = ((hh + 2 * c) ^ x7) << 4;

    f32x16 o[2], zvec;
    float lsum = 0.f;
    #pragma unroll
    for (int i = 0; i < 16; ++i) { o[0][i] = 0.f; o[1][i] = 0.f; zvec[i] = 0.f; }

    auto STAGE = [&](int t) {
        size_t kb = (size_t)t * 64;
        char* dk = (char*)lK[t & 1] + w * 2048;
        char* dv = (char*)lV[t & 1] + w * 2048;
        __builtin_amdgcn_global_load_lds(GPTR(ksrc0 + kb * D_MODEL), LPTR(dk), 16, 0, 0);
        __builtin_amdgcn_global_load_lds(GPTR(ksrc1 + kb * D_MODEL), LPTR(dk + 1024), 16, 0, 0);
        __builtin_amdgcn_global_load_lds(GPTR(vsrc0 + kb), LPTR(dv), 16, 0, 0);
        __builtin_amdgcn_global_load_lds(GPTR(vsrc1 + kb), LPTR(dv + 1024), 16, 0, 0);
    };

    STAGE(0);
    __syncthreads();

    for (int t = 0; t < 16; ++t) {
        if (t < 15) STAGE(t + 1);
        const char* lKc = (const char*)lK[t & 1];
        const char* lVc = (const char*)lV[t & 1];
        #pragma unroll
        for (int half = 0; half < 2; ++half) {
            // ---- QK: S^T (32 kv x 32 q), chain of 4 ----
            f32x16 s;
            __builtin_amdgcn_s_setprio(1);
            {
                bf16x8 kf = *(const bf16x8*)(lKc + (half * 32 + l31) * 128 + chv[0]);
                s = __builtin_amdgcn_mfma_f32_32x32x16_bf16(kf, qf[0], zvec, 0, 0, 0);
            }
            #pragma unroll
            for (int c = 1; c < 4; ++c) {
                bf16x8 kf = *(const bf16x8*)(lKc + (half * 32 + l31) * 128 + chv[c]);
                s = __builtin_amdgcn_mfma_f32_32x32x16_bf16(kf, qf[c], s, 0, 0, 0);
            }
            __builtin_amdgcn_s_setprio(0);
            // ---- softmax: P = exp2(S), lane L-sum, pack to 2 B-fragments ----
            float pr[16];
            #pragma unroll
            for (int r = 0; r < 16; ++r) pr[r] = FEXP2(s[r]);
            float s0 = (pr[0] + pr[1]) + (pr[2] + pr[3]);
            float s1 = (pr[4] + pr[5]) + (pr[6] + pr[7]);
            float s2 = (pr[8] + pr[9]) + (pr[10] + pr[11]);
            float s3 = (pr[12] + pr[13]) + (pr[14] + pr[15]);
            lsum += (s0 + s1) + (s2 + s3);
            bf16x8 pfr[2];
            #pragma unroll
            for (int sl = 0; sl < 2; ++sl) {
                unsigned pA = cvt_pk_bf16(pr[sl * 8 + 0], pr[sl * 8 + 1]);
                unsigned pB = cvt_pk_bf16(pr[sl * 8 + 2], pr[sl * 8 + 3]);
                unsigned pC = cvt_pk_bf16(pr[sl * 8 + 4], pr[sl * 8 + 5]);
                unsigned pD = cvt_pk_bf16(pr[sl * 8 + 6], pr[sl * 8 + 7]);
                asm("v_permlane32_swap_b32 %0, %1" : "+v"(pA), "+v"(pC));
                asm("v_permlane32_swap_b32 %0, %1" : "+v"(pB), "+v"(pD));
                union { unsigned u[4]; bf16x8 v; } pf;
                pf.u[0] = pA; pf.u[1] = pB; pf.u[2] = pC; pf.u[3] = pD;
                pfr[sl] = pf.v;
            }
            // ---- PV ----
            __builtin_amdgcn_s_setprio(1);
            #pragma unroll
            for (int sl = 0; sl < 2; ++sl) {
                int ks = half * 2 + sl;
                #pragma unroll
                for (int dblk = 0; dblk < 2; ++dblk) {
                    bf16x8 vf = *(const bf16x8*)(lVc + (dblk * 32 + l31) * 128 + chv[ks]);
                    o[dblk] = __builtin_amdgcn_mfma_f32_32x32x16_bf16(vf, pfr[sl], o[dblk], 0, 0, 0);
                }
            }
            __builtin_amdgcn_s_setprio(0);
        }
        __syncthreads();   // drains prefetch; protects ring-2 reuse
    }

    // ---- partial outputs ----
    float Lt = lsum + __shfl_xor(lsum, 32);
    size_t tok = (size_t)(b * T_SEQ) + qrow;
    if (hh == 0) Lp[(size_t)p * (MTOK * NH) + tok * NH + h] = Lt;
    size_t ebase = tok * D_MODEL + h * HD + 4 * hh;
    if (p == 0) {
        #pragma unroll
        for (int dblk = 0; dblk < 2; ++dblk)
            #pragma unroll
            for (int g = 0; g < 4; ++g) {
                float4 ov;
                ov.x = o[dblk][4 * g + 0];
                ov.y = o[dblk][4 * g + 1];
                ov.z = o[dblk][4 * g + 2];
                ov.w = o[dblk][4 * g + 3];
                *(float4*)(o32 + ebase + dblk * 32 + 8 * g) = ov;
            }
    } else {
        #pragma unroll
        for (int dblk = 0; dblk < 2; ++dblk)
            #pragma unroll
            for (int g = 0; g < 4; ++g) {
                ushort4 ov;
                ov.x = f2bf(o[dblk][4 * g + 0]);
                ov.y = f2bf(o[dblk][4 * g + 1]);
                ov.z = f2bf(o[dblk][4 * g + 2]);
                ov.w = f2bf(o[dblk][4 * g + 3]);
                *(ushort4*)(o16 + ebase + dblk * 32 + 8 * g) = ov;
            }
    }
}

// ---------------- Combine: out = x + (O0 + O1) / (L0 + L1) ----------------
__global__ __launch_bounds__(256) void combine_kernel(const float* __restrict__ x,
                                                      const ushort* __restrict__ o16,
                                                      const float* __restrict__ Lp,
                                                      float* __restrict__ out) {
    int i = blockIdx.x * 256 + threadIdx.x;   // float4 index, 2^20 total
    int tok = i >> 8;
    int h = (i >> 4) & 15;
    size_t li = (size_t)tok * NH + h;
    float l = Lp[li] + Lp[(size_t)(MTOK * NH) + li];
    float inv = 1.0f / l;
    float4 o0 = ((const float4*)out)[i];
    ushort4 u = ((const ushort4*)o16)[i];
    float4 xv = ((const float4*)x)[i];
    float4 r;
    r.x = xv.x + (o0.x + bf2f(u.x)) * inv;
    r.y = xv.y + (o0.y + bf2f(u.y)) * inv;
    r.z = xv.z + (o0.z + bf2f(u.z)) * inv;
    r.w = xv.w + (o0.w + bf2f(u.w)) * inv;
    ((float4*)out)[i] = r;
}

extern "C" void kernel_launch(void* const* d_in, const int* in_sizes, int n_in,
                              void* d_out, int out_size, void* d_ws, size_t ws_size,
                              hipStream_t stream) {
    const float* x     = (const float*)d_in[0];
    const float* Wq    = (const float*)d_in[1];
    const float* Wk    = (const float*)d_in[2];
    const float* Wv    = (const float*)d_in[3];
    const float* gamma = (const float*)d_in[4];
    const float* beta  = (const float*)d_in[5];
    float* out = (float*)d_out;

    char* ws = (char*)d_ws;
    ushort* xn  = (ushort*)(ws);                 // 8 MB; dead after gemm -> reused as O1 partials
    ushort* wqb = (ushort*)(ws + (8  << 20));    // 2 MB; dead after gemm -> reused as L partials
    ushort* wkb = (ushort*)(ws + (10 << 20));
    ushort* wvb = (ushort*)(ws + (12 << 20));
    ushort* Qb  = (ushort*)(ws + (14 << 20));
    ushort* Kb  = (ushort*)(ws + (22 << 20));
    ushort* Vtb = (ushort*)(ws + (30 << 20));    // V^T [1024][4096]

    ushort* o16 = (ushort*)(ws);                 // 8 MB bf16 O1 partial (over xn)
    float*  Lp  = (float*)(ws + (8 << 20));      // 512 KB L0|L1 (over wqb)

    int M = NB * T_SEQ;

    prep_kernel<<<dim3(MTOK + 3072), 256, 0, stream>>>(x, gamma, beta, xn,
                                                       Wq, Wk, Wv, wqb, wkb, wvb);
    gemm_qkv<<<dim3(M / 128, D_MODEL / 128, 3), 256, 0, stream>>>(
        xn, wqb, wkb, wvb, Qb, Kb, Vtb, M, D_MODEL, D_MODEL);
    attn_kernel<<<dim3(1024), 256, 0, stream>>>(Qb, Kb, Vtb, out, o16, Lp);
    combine_kernel<<<dim3(4096), 256, 0, stream>>>(x, o16, Lp, out);
}

// Round 13
// 96.149 us; speedup vs baseline: 1.1173x; 1.1173x over previous
//
#include <hip/hip_runtime.h>
#include <hip/hip_bf16.h>
#include <stdint.h>

#define D_MODEL 1024
#define T_SEQ   2048
#define NB      2
#define NH      16
#define HD      64
#define MTOK    4096   // NB*T_SEQ

typedef __bf16  bf16x8 __attribute__((ext_vector_type(8)));
typedef float   f32x4  __attribute__((ext_vector_type(4)));
typedef float   f32x16 __attribute__((ext_vector_type(16)));

#define GPTR(p) ((const __attribute__((address_space(1))) void*)(p))
#define LPTR(p) ((__attribute__((address_space(3))) void*)(p))

static __device__ __forceinline__ ushort f2bf(float f) {
    union { float f; uint32_t u; } c{f};
    uint32_t u = c.u;
    return (ushort)((u + 0x7fff + ((u >> 16) & 1)) >> 16);
}

static __device__ __forceinline__ unsigned cvt_pk_bf16(float lo, float hi) {
    unsigned r;
    asm("v_cvt_pk_bf16_f32 %0, %1, %2" : "=v"(r) : "v"(lo), "v"(hi));
    return r;
}

#if defined(__has_builtin)
#if __has_builtin(__builtin_amdgcn_exp2f)
#define FEXP2(x) __builtin_amdgcn_exp2f(x)
#endif
#endif
#ifndef FEXP2
static __device__ __forceinline__ float fexp2_asm(float x) {
    float r;
    asm("v_exp_f32 %0, %1" : "=v"(r) : "v"(x));
    return r;
}
#define FEXP2(x) fexp2_asm(x)
#endif

// ---------------- Fused prep: LN rows + weight bf16 conversion ----------------
__global__ __launch_bounds__(256) void prep_kernel(const float* __restrict__ x,
                                                   const float* __restrict__ gamma,
                                                   const float* __restrict__ beta,
                                                   ushort* __restrict__ xn,
                                                   const float* __restrict__ a0,
                                                   const float* __restrict__ a1,
                                                   const float* __restrict__ a2,
                                                   ushort* __restrict__ o0,
                                                   ushort* __restrict__ o1,
                                                   ushort* __restrict__ o2) {
    int blk = blockIdx.x;
    int tid = threadIdx.x;
    if (blk >= MTOK) {
        int z = (blk - MTOK) >> 10;
        int cb = (blk - MTOK) & 1023;
        const float* a = (z == 0) ? a0 : (z == 1) ? a1 : a2;
        ushort* o = (z == 0) ? o0 : (z == 1) ? o1 : o2;
        int i = cb * 256 + tid;
        float4 v = ((const float4*)a)[i];
        ushort4 r;
        r.x = f2bf(v.x); r.y = f2bf(v.y); r.z = f2bf(v.z); r.w = f2bf(v.w);
        ((ushort4*)o)[i] = r;
        return;
    }
    int row = blk;
    const float4* xr = (const float4*)(x + (size_t)row * D_MODEL);
    float4 v = xr[tid];
    float s  = v.x + v.y + v.z + v.w;
    float ss = v.x * v.x + v.y * v.y + v.z * v.z + v.w * v.w;
    #pragma unroll
    for (int m = 1; m < 64; m <<= 1) {
        s  += __shfl_xor(s, m);
        ss += __shfl_xor(ss, m);
    }
    __shared__ float red[8];
    int w = tid >> 6, lane = tid & 63;
    if (lane == 0) { red[w] = s; red[4 + w] = ss; }
    __syncthreads();
    s  = red[0] + red[1] + red[2] + red[3];
    ss = red[4] + red[5] + red[6] + red[7];
    float mu   = s * (1.0f / D_MODEL);
    float var  = ss * (1.0f / D_MODEL) - mu * mu;
    float rstd = rsqrtf(var + 1e-5f);
    float4 g = ((const float4*)gamma)[tid];
    float4 b = ((const float4*)beta)[tid];
    ushort4 o;
    o.x = f2bf((v.x - mu) * rstd * g.x + b.x);
    o.y = f2bf((v.y - mu) * rstd * g.y + b.y);
    o.z = f2bf((v.z - mu) * rstd * g.z + b.z);
    o.w = f2bf((v.w - mu) * rstd * g.w + b.w);
    ((ushort4*)(xn + (size_t)row * D_MODEL))[tid] = o;
}

// ---------------- QKV GEMM (round-9 structure, unchanged) ----------------
__global__ __launch_bounds__(256) void gemm_qkv(const ushort* __restrict__ A,
                                                const ushort* __restrict__ w0,
                                                const ushort* __restrict__ w1,
                                                const ushort* __restrict__ w2,
                                                ushort* __restrict__ c0,
                                                ushort* __restrict__ c1,
                                                ushort* __restrict__ c2,
                                                int M, int N, int K) {
    const ushort* Bw = (blockIdx.z == 0) ? w0 : (blockIdx.z == 1) ? w1 : w2;
    ushort* C = (blockIdx.z == 0) ? c0 : (blockIdx.z == 1) ? c1 : c2;

    __shared__ __align__(16) ushort lA[2][128 * 64];
    __shared__ __align__(16) ushort lB[2][128 * 64];
    int tid = threadIdx.x;
    int w = tid >> 6, lane = tid & 63;
    int wr = w >> 1, wc = w & 1;
    int l15 = lane & 15, l4 = lane >> 4;
    int row0 = blockIdx.x * 128, col0 = blockIdx.y * 128;

    f32x4 zero = {0.f, 0.f, 0.f, 0.f};
    f32x4 acc[4][4];
    #pragma unroll
    for (int i = 0; i < 4; ++i)
        #pragma unroll
        for (int j = 0; j < 4; ++j) acc[i][j] = zero;

    int sr  = tid >> 3;
    int scc = (((tid & 7) ^ (sr & 7)) << 3);
    int rch[2];
    rch[0] = ((l4)     ^ (l15 & 7)) << 4;
    rch[1] = ((4 + l4) ^ (l15 & 7)) << 4;

    auto STAGE = [&](int buf, int kt) {
        int k0 = kt * 64;
        #pragma unroll
        for (int i = 0; i < 4; ++i) {
            int r = i * 32 + sr;
            const ushort* ga = A + (size_t)(row0 + r) * K + k0 + scc;
            __builtin_amdgcn_global_load_lds(GPTR(ga), LPTR((char*)lA[buf] + i * 4096 + tid * 16), 16, 0, 0);
            const ushort* gb = Bw + (size_t)(col0 + r) * K + k0 + scc;
            __builtin_amdgcn_global_load_lds(GPTR(gb), LPTR((char*)lB[buf] + i * 4096 + tid * 16), 16, 0, 0);
        }
    };

    STAGE(0, 0);
    __syncthreads();

    int buf = 0;
    const int NK = K / 64;
    for (int kt = 0; kt < NK; ++kt) {
        if (kt + 1 < NK) STAGE(buf ^ 1, kt + 1);
        const char* la  = (const char*)lA[buf];
        const char* lb_ = (const char*)lB[buf];
        __builtin_amdgcn_s_setprio(1);
        #pragma unroll
        for (int ks = 0; ks < 2; ++ks) {
            bf16x8 af[4], bfr[4];
            #pragma unroll
            for (int i = 0; i < 4; ++i) {
                int ra = wr * 64 + i * 16 + l15;
                int rb = wc * 64 + i * 16 + l15;
                af[i]  = *(const bf16x8*)(la  + ra * 128 + rch[ks]);
                bfr[i] = *(const bf16x8*)(lb_ + rb * 128 + rch[ks]);
            }
            #pragma unroll
            for (int i = 0; i < 4; ++i)
                #pragma unroll
                for (int j = 0; j < 4; ++j)
                    acc[i][j] = __builtin_amdgcn_mfma_f32_16x16x32_bf16(af[i], bfr[j], acc[i][j], 0, 0, 0);
        }
        __builtin_amdgcn_s_setprio(0);
        __syncthreads();
        buf ^= 1;
    }

    if (blockIdx.z == 2) {
        #pragma unroll
        for (int i = 0; i < 4; ++i) {
            int rbase = row0 + wr * 64 + i * 16 + l4 * 4;
            #pragma unroll
            for (int j = 0; j < 4; ++j) {
                int col = col0 + wc * 64 + j * 16 + l15;
                ushort4 o4;
                o4.x = f2bf(acc[i][j][0]);
                o4.y = f2bf(acc[i][j][1]);
                o4.z = f2bf(acc[i][j][2]);
                o4.w = f2bf(acc[i][j][3]);
                *(ushort4*)&C[(size_t)col * M + rbase] = o4;
            }
        }
    } else {
        float sc = (blockIdx.z == 0) ? 0.18033688011112042f : 1.0f;
        #pragma unroll
        for (int i = 0; i < 4; ++i) {
            int rbase = row0 + wr * 64 + i * 16 + l4 * 4;
            #pragma unroll
            for (int j = 0; j < 4; ++j) {
                int col = col0 + wc * 64 + j * 16 + l15;
                #pragma unroll
                for (int r = 0; r < 4; ++r)
                    C[(size_t)(rbase + r) * N + col] = f2bf(acc[i][j][r] * sc);
            }
        }
    }
}

// ---------------- Flash attention + residual (8-wave shared-KV) ----------
// Grid 256 blocks (1/CU, XCD-chunked: 8 qt-blocks of each (b,h) on one XCD),
// 512 threads = 8 waves x 32 q-rows = 256 q-rows/block, FULL KV per block.
// K/V staged ONCE per block serve 8 waves (halves per-CU LDS read traffic vs
// 4-wave). Ring-4 LDS, tile pairs per barrier, QK;QK;SMPV;SMPV pipeline,
// in-register P (cvt_pk + permlane32_swap), no-max softmax, own epilogue.
__global__ __launch_bounds__(512, 2) void attn_kernel(const ushort* __restrict__ Q,
                                                      const ushort* __restrict__ Km,
                                                      const ushort* __restrict__ Vt,
                                                      const float* __restrict__ x,
                                                      float* __restrict__ out) {
    int bid = blockIdx.x;
    int sw  = (bid & 7) * 32 + (bid >> 3);    // 8 XCD chunks of 32 blocks
    int qt = sw & 7, h = (sw >> 3) & 15, b = sw >> 7;

    int tid = threadIdx.x, w = tid >> 6, lane = tid & 63;
    int l31 = lane & 31, hh = lane >> 5, x7 = lane & 7;
    size_t head_off = (size_t)b * T_SEQ * D_MODEL + (size_t)h * HD;
    const ushort* Qh  = Q  + head_off;
    const ushort* Kh  = Km + head_off;
    const ushort* Vth = Vt + (size_t)h * HD * MTOK + (size_t)b * T_SEQ;  // [d][tok]

    __shared__ __align__(16) ushort lK[4][64 * 64];   // ring-4, 32 KB
    __shared__ __align__(16) ushort lV[4][64 * 64];   // ring-4, 32 KB

    int qrow = qt * 256 + w * 32 + l31;
    bf16x8 qf[4];
    #pragma unroll
    for (int c = 0; c < 4; ++c)
        qf[c] = *(const bf16x8*)&Qh[(size_t)qrow * D_MODEL + hh * 8 + c * 16];

    // staging: thread tid stages chunk tid of each 8KB tile (512 chunks).
    // dest (row=tid>>3, chunk=tid&7) holds global chunk (tid&7)^(row&7).
    int r0  = tid >> 3;
    int cg0 = (tid & 7) ^ (r0 & 7);
    const ushort* ksrc = Kh  + (size_t)r0 * D_MODEL + cg0 * 8;
    const ushort* vsrc = Vth + (size_t)r0 * MTOK + cg0 * 8;

    int chv[4];
    #pragma unroll
    for (int c = 0; c < 4; ++c) chv[c] = ((hh + 2 * c) ^ x7) << 4;

    f32x16 oa[2], ob[2], zvec;
    float la = 0.f, lb = 0.f;
    #pragma unroll
    for (int i = 0; i < 16; ++i) {
        oa[0][i] = 0.f; oa[1][i] = 0.f; ob[0][i] = 0.f; ob[1][i] = 0.f;
        zvec[i] = 0.f;
    }

    auto STAGE = [&](int t) {
        size_t kb = (size_t)t * 64;
        __builtin_amdgcn_global_load_lds(GPTR(ksrc + kb * D_MODEL), LPTR((char*)lK[t & 3] + tid * 16), 16, 0, 0);
        __builtin_amdgcn_global_load_lds(GPTR(vsrc + kb), LPTR((char*)lV[t & 3] + tid * 16), 16, 0, 0);
    };

    auto QK = [&](int t, f32x16& sa, f32x16& sb) {
        const char* lKc = (const char*)lK[t & 3];
        __builtin_amdgcn_s_setprio(1);
        {
            bf16x8 ka  = *(const bf16x8*)(lKc + l31 * 128 + chv[0]);
            bf16x8 kb2 = *(const bf16x8*)(lKc + (32 + l31) * 128 + chv[0]);
            sa = __builtin_amdgcn_mfma_f32_32x32x16_bf16(ka,  qf[0], zvec, 0, 0, 0);
            sb = __builtin_amdgcn_mfma_f32_32x32x16_bf16(kb2, qf[0], zvec, 0, 0, 0);
        }
        #pragma unroll
        for (int c = 1; c < 4; ++c) {
            bf16x8 ka  = *(const bf16x8*)(lKc + l31 * 128 + chv[c]);
            bf16x8 kb2 = *(const bf16x8*)(lKc + (32 + l31) * 128 + chv[c]);
            sa = __builtin_amdgcn_mfma_f32_32x32x16_bf16(ka,  qf[c], sa, 0, 0, 0);
            sb = __builtin_amdgcn_mfma_f32_32x32x16_bf16(kb2, qf[c], sb, 0, 0, 0);
        }
        __builtin_amdgcn_s_setprio(0);
    };

    auto SMPV = [&](int t, const f32x16& sa, const f32x16& sb) {
        const char* lVc = (const char*)lV[t & 3];
        bf16x8 vfr[4][2];
        #pragma unroll
        for (int ks = 0; ks < 4; ++ks)
            #pragma unroll
            for (int dblk = 0; dblk < 2; ++dblk)
                vfr[ks][dblk] = *(const bf16x8*)(lVc + (dblk * 32 + l31) * 128 + chv[ks]);

        bf16x8 pfr[4];
        #pragma unroll
        for (int kbb = 0; kbb < 2; ++kbb) {
            float pr[16];
            #pragma unroll
            for (int r = 0; r < 16; ++r) pr[r] = FEXP2(kbb ? sb[r] : sa[r]);
            float s0 = (pr[0] + pr[1]) + (pr[2] + pr[3]);
            float s1 = (pr[4] + pr[5]) + (pr[6] + pr[7]);
            float s2 = (pr[8] + pr[9]) + (pr[10] + pr[11]);
            float s3 = (pr[12] + pr[13]) + (pr[14] + pr[15]);
            if (kbb == 0) la += (s0 + s1) + (s2 + s3);
            else          lb += (s0 + s1) + (s2 + s3);
            #pragma unroll
            for (int sl = 0; sl < 2; ++sl) {
                unsigned pA = cvt_pk_bf16(pr[sl * 8 + 0], pr[sl * 8 + 1]);
                unsigned pB = cvt_pk_bf16(pr[sl * 8 + 2], pr[sl * 8 + 3]);
                unsigned pC = cvt_pk_bf16(pr[sl * 8 + 4], pr[sl * 8 + 5]);
                unsigned pD = cvt_pk_bf16(pr[sl * 8 + 6], pr[sl * 8 + 7]);
                asm("v_permlane32_swap_b32 %0, %1" : "+v"(pA), "+v"(pC));
                asm("v_permlane32_swap_b32 %0, %1" : "+v"(pB), "+v"(pD));
                union { unsigned u[4]; bf16x8 v; } pf;
                pf.u[0] = pA; pf.u[1] = pB; pf.u[2] = pC; pf.u[3] = pD;
                pfr[kbb * 2 + sl] = pf.v;
            }
        }
        __builtin_amdgcn_s_setprio(1);
        #pragma unroll
        for (int ks = 0; ks < 4; ++ks) {
            #pragma unroll
            for (int dblk = 0; dblk < 2; ++dblk) {
                if (ks & 1)
                    ob[dblk] = __builtin_amdgcn_mfma_f32_32x32x16_bf16(vfr[ks][dblk], pfr[ks], ob[dblk], 0, 0, 0);
                else
                    oa[dblk] = __builtin_amdgcn_mfma_f32_32x32x16_bf16(vfr[ks][dblk], pfr[ks], oa[dblk], 0, 0, 0);
            }
        }
        __builtin_amdgcn_s_setprio(0);
    };

    STAGE(0);
    STAGE(1);
    __syncthreads();

    const int NT = T_SEQ / 64;   // 32 tiles, 16 pairs
    for (int s = 0; s < NT / 2; ++s) {
        int t0 = 2 * s;
        if (s < NT / 2 - 1) { STAGE(t0 + 2); STAGE(t0 + 3); }
        f32x16 sa0, sb0, sa1, sb1;
        QK(t0, sa0, sb0);
        QK(t0 + 1, sa1, sb1);
        SMPV(t0, sa0, sb0);
        SMPV(t0 + 1, sa1, sb1);
        __syncthreads();
    }

    float Lt = la + lb;
    float Lfull = Lt + __shfl_xor(Lt, 32);
    float inv = 1.0f / Lfull;
    const float* xrow = x   + (size_t)(b * T_SEQ + qrow) * D_MODEL + h * HD + 4 * hh;
    float*       orow = out + (size_t)(b * T_SEQ + qrow) * D_MODEL + h * HD + 4 * hh;
    #pragma unroll
    for (int dblk = 0; dblk < 2; ++dblk) {
        #pragma unroll
        for (int g = 0; g < 4; ++g) {
            int coff = dblk * 32 + 8 * g;
            float4 xv = *(const float4*)(xrow + coff);
            float4 ov;
            ov.x = xv.x + (oa[dblk][4 * g + 0] + ob[dblk][4 * g + 0]) * inv;
            ov.y = xv.y + (oa[dblk][4 * g + 1] + ob[dblk][4 * g + 1]) * inv;
            ov.z = xv.z + (oa[dblk][4 * g + 2] + ob[dblk][4 * g + 2]) * inv;
            ov.w = xv.w + (oa[dblk][4 * g + 3] + ob[dblk][4 * g + 3]) * inv;
            *(float4*)(orow + coff) = ov;
        }
    }
}

extern "C" void kernel_launch(void* const* d_in, const int* in_sizes, int n_in,
                              void* d_out, int out_size, void* d_ws, size_t ws_size,
                              hipStream_t stream) {
    const float* x     = (const float*)d_in[0];
    const float* Wq    = (const float*)d_in[1];
    const float* Wk    = (const float*)d_in[2];
    const float* Wv    = (const float*)d_in[3];
    const float* gamma = (const float*)d_in[4];
    const float* beta  = (const float*)d_in[5];
    float* out = (float*)d_out;

    char* ws = (char*)d_ws;
    ushort* xn  = (ushort*)(ws);
    ushort* wqb = (ushort*)(ws + (8  << 20));
    ushort* wkb = (ushort*)(ws + (10 << 20));
    ushort* wvb = (ushort*)(ws + (12 << 20));
    ushort* Qb  = (ushort*)(ws + (14 << 20));
    ushort* Kb  = (ushort*)(ws + (22 << 20));
    ushort* Vtb = (ushort*)(ws + (30 << 20));   // V^T [1024][4096]

    int M = NB * T_SEQ;

    prep_kernel<<<dim3(MTOK + 3072), 256, 0, stream>>>(x, gamma, beta, xn,
                                                       Wq, Wk, Wv, wqb, wkb, wvb);
    gemm_qkv<<<dim3(M / 128, D_MODEL / 128, 3), 256, 0, stream>>>(
        xn, wqb, wkb, wvb, Qb, Kb, Vtb, M, D_MODEL, D_MODEL);
    attn_kernel<<<dim3(256), 512, 0, stream>>>(Qb, Kb, Vtb, x, out);
}